// Round 1
// baseline (166.051 us; speedup 1.0000x reference)
//
#include <hip/hip_runtime.h>
#include <hip/hip_bf16.h>

#define NE   64
#define HDIM 4096
#define NTOK 16384
// tokens-per-batch = sq = 4096 -> batch = token >> 12

// ---------------------------------------------------------------------------
// GEMM: logits partials.
// Grid: 128 token-blocks * ksplit.  Block: 256 threads (16x16).
// Tile: 128 tokens x 64 experts, K chunked by 32 into LDS.
// Thread register tile: 8 tokens x 4 experts (32 fp32 acc).
// ---------------------------------------------------------------------------
__global__ __launch_bounds__(256, 2) void gemm_logits(
    const float* __restrict__ x, const float* __restrict__ W,
    float* __restrict__ part, int ksplit, int kper) {
    __shared__ float xst[32][128];   // [k][token]  row = 512B, 16B-aligned
    __shared__ float wt[32][64];     // [k][expert] row = 256B

    const int tid = threadIdx.x;
    const int bk  = blockIdx.x % ksplit;
    const int bt  = blockIdx.x / ksplit;
    const int t0  = bt * 128;
    const int kbase = bk * kper;

    const int ti = tid >> 4;         // 0..15 token group
    const int tj = tid & 15;         // 0..15 expert group
    const int kq = tid & 7;          // float4 index along k for staging
    const int rr = tid >> 3;         // 0..31 row for staging

    float acc[8][4];
#pragma unroll
    for (int m = 0; m < 8; ++m)
#pragma unroll
        for (int n = 0; n < 4; ++n) acc[m][n] = 0.f;

    for (int kc = 0; kc < kper; kc += 32) {
        const int k0 = kbase + kc;
        // stage x tile: 128 tokens x 32 k (coalesced read along k, transpose into LDS)
#pragma unroll
        for (int p = 0; p < 4; ++p) {
            const int r = p * 32 + rr;
            const float4 v = *reinterpret_cast<const float4*>(
                &x[(size_t)(t0 + r) * HDIM + k0 + kq * 4]);
            xst[kq * 4 + 0][r] = v.x;
            xst[kq * 4 + 1][r] = v.y;
            xst[kq * 4 + 2][r] = v.z;
            xst[kq * 4 + 3][r] = v.w;
        }
        // stage W tile: 64 experts x 32 k
#pragma unroll
        for (int p = 0; p < 2; ++p) {
            const int e = p * 32 + rr;
            const float4 v = *reinterpret_cast<const float4*>(
                &W[(size_t)e * HDIM + k0 + kq * 4]);
            wt[kq * 4 + 0][e] = v.x;
            wt[kq * 4 + 1][e] = v.y;
            wt[kq * 4 + 2][e] = v.z;
            wt[kq * 4 + 3][e] = v.w;
        }
        __syncthreads();

#pragma unroll
        for (int k = 0; k < 32; ++k) {
            const float4 xa = *reinterpret_cast<const float4*>(&xst[k][ti * 8]);
            const float4 xb = *reinterpret_cast<const float4*>(&xst[k][ti * 8 + 4]);
            const float4 wv = *reinterpret_cast<const float4*>(&wt[k][tj * 4]);
            const float xs8[8] = {xa.x, xa.y, xa.z, xa.w, xb.x, xb.y, xb.z, xb.w};
            const float ws4[4] = {wv.x, wv.y, wv.z, wv.w};
#pragma unroll
            for (int m = 0; m < 8; ++m)
#pragma unroll
                for (int n = 0; n < 4; ++n)
                    acc[m][n] = fmaf(xs8[m], ws4[n], acc[m][n]);
        }
        __syncthreads();
    }

    // write partial logits: part[bk][token][expert]
    float* base = part + (size_t)bk * NTOK * NE;
#pragma unroll
    for (int m = 0; m < 8; ++m) {
        const int t = t0 + ti * 8 + m;
        float4 v;
        v.x = acc[m][0]; v.y = acc[m][1]; v.z = acc[m][2]; v.w = acc[m][3];
        *reinterpret_cast<float4*>(&base[(size_t)t * NE + tj * 4]) = v;
    }
}

// ---------------------------------------------------------------------------
// Router: thread-per-token. Sum partials -> logits; softmax*mask -> scores;
// top-2 (jax tie-break: lowest index first); softmax over top-2 + L1 renorm.
// Output layout (fp32 flat): [scores 16384*64][logits 16384*64][weights 16384*2][indices 16384*2]
// ---------------------------------------------------------------------------
__global__ __launch_bounds__(256) void router_kernel(
    const float* __restrict__ part, const float* __restrict__ mask,
    float* __restrict__ out, int ksplit) {
    const int t = blockIdx.x * 256 + threadIdx.x;
    if (t >= NTOK) return;

    float l[NE];
#pragma unroll
    for (int e4 = 0; e4 < NE / 4; ++e4) {
        const float4 v = *reinterpret_cast<const float4*>(
            &part[(size_t)t * NE + e4 * 4]);
        l[e4 * 4 + 0] = v.x; l[e4 * 4 + 1] = v.y;
        l[e4 * 4 + 2] = v.z; l[e4 * 4 + 3] = v.w;
    }
    for (int c = 1; c < ksplit; ++c) {
#pragma unroll
        for (int e4 = 0; e4 < NE / 4; ++e4) {
            const float4 v = *reinterpret_cast<const float4*>(
                &part[((size_t)c * NTOK + t) * NE + e4 * 4]);
            l[e4 * 4 + 0] += v.x; l[e4 * 4 + 1] += v.y;
            l[e4 * 4 + 2] += v.z; l[e4 * 4 + 3] += v.w;
        }
    }

    // write logits
    float* lo = out + (size_t)NTOK * NE + (size_t)t * NE;
#pragma unroll
    for (int e4 = 0; e4 < NE / 4; ++e4) {
        float4 v;
        v.x = l[e4 * 4 + 0]; v.y = l[e4 * 4 + 1];
        v.z = l[e4 * 4 + 2]; v.w = l[e4 * 4 + 3];
        *reinterpret_cast<float4*>(&lo[e4 * 4]) = v;
    }

    // softmax over 64
    float mx = l[0];
#pragma unroll
    for (int e = 1; e < NE; ++e) mx = fmaxf(mx, l[e]);
    float sc[NE];
    float s = 0.f;
#pragma unroll
    for (int e = 0; e < NE; ++e) {
        const float ev = expf(l[e] - mx);
        sc[e] = ev;
        s += ev;
    }
    const float inv = 1.f / s;
    const float* mrow = mask + (size_t)(t >> 12) * NE;
#pragma unroll
    for (int e = 0; e < NE; ++e) sc[e] = mrow[e] * (sc[e] * inv);

    // write scores
    float* so = out + (size_t)t * NE;
#pragma unroll
    for (int e4 = 0; e4 < NE / 4; ++e4) {
        float4 v;
        v.x = sc[e4 * 4 + 0]; v.y = sc[e4 * 4 + 1];
        v.z = sc[e4 * 4 + 2]; v.w = sc[e4 * 4 + 3];
        *reinterpret_cast<float4*>(&so[e4 * 4]) = v;
    }

    // top-2 scan (strict > keeps lowest index on ties, matching jax.lax.top_k)
    float v1 = -3.4e38f, v2 = -3.4e38f;
    int i1 = 0, i2 = 0;
#pragma unroll
    for (int e = 0; e < NE; ++e) {
        const float v = sc[e];
        if (v > v1) {
            v2 = v1; i2 = i1;
            v1 = v;  i1 = e;
        } else if (v > v2) {
            v2 = v; i2 = e;
        }
    }

    // softmax over [v1, v2] (v1 >= v2) then L1 renorm (idempotent, kept for parity)
    const float e2 = expf(v2 - v1);
    float w1 = 1.f / (1.f + e2);
    float w2 = e2 / (1.f + e2);
    const float sw = w1 + w2;
    w1 /= sw; w2 /= sw;

    const size_t wo = (size_t)2 * NTOK * NE;
    out[wo + (size_t)t * 2 + 0] = w1;
    out[wo + (size_t)t * 2 + 1] = w2;
    const size_t io = wo + (size_t)NTOK * 2;
    out[io + (size_t)t * 2 + 0] = (float)i1;
    out[io + (size_t)t * 2 + 1] = (float)i2;
}

extern "C" void kernel_launch(void* const* d_in, const int* in_sizes, int n_in,
                              void* d_out, int out_size, void* d_ws, size_t ws_size,
                              hipStream_t stream) {
    const float* x    = (const float*)d_in[0];
    const float* mask = (const float*)d_in[1];
    const float* W    = (const float*)d_in[2];
    float* out  = (float*)d_out;
    float* part = (float*)d_ws;

    const size_t per_split = (size_t)NTOK * NE * sizeof(float); // 4 MB
    int ksplit = 1;
    if (ws_size >= 4 * per_split) ksplit = 4;
    else if (ws_size >= 2 * per_split) ksplit = 2;
    const int kper = HDIM / ksplit;

    gemm_logits<<<dim3(128 * ksplit), dim3(256), 0, stream>>>(x, W, part, ksplit, kper);
    router_kernel<<<dim3(NTOK / 256), dim3(256), 0, stream>>>(part, mask, out, ksplit);
}